// Round 6
// baseline (3545.710 us; speedup 1.0000x reference)
//
#include <hip/hip_runtime.h>
#include <hip/hip_fp16.h>

// Problem sizes
#define B_SZ 32
#define L_SZ 512
#define D_SZ 1024
#define H_SZ 1024
#define NG   4096           // 4*H
#define M_SZ 16384          // B*L

typedef __attribute__((ext_vector_type(8))) short short8;
typedef __attribute__((ext_vector_type(4))) float f32x4;
typedef __attribute__((ext_vector_type(4))) unsigned u32x4;
typedef __attribute__((ext_vector_type(4))) unsigned short u16x4;

// Workspace layout (bytes). Total ~184.7 MB.
// XB region doubles as the h RING BUFFER (512 slots x 64 KB = 32 MiB) once
// k_xgemm has consumed the bf16 x data.
static const size_t GX_OFF  = 0;                  // Gx fp16: 16384*4096*2 = 134217728
static const size_t XB_OFF  = 134217728;          // x bf16 / h ring: 33554432
static const size_t WH_OFF  = 167772160;          // Wh bf16: 8388608
static const size_t WX_OFF  = 176160768;          // Wx bf16: 8388608
static const size_t FLG_OFF = 184680448;          // flags: 128 x 64B = 8192

__device__ __forceinline__ unsigned short f2bf(float f) {
  union { float f; unsigned u; } v; v.f = f;
  unsigned r = v.u + 0x7fffu + ((v.u >> 16) & 1u);
  return (unsigned short)(r >> 16);
}

__device__ __forceinline__ void gload_lds16(const void* g, void* l) {
  __builtin_amdgcn_global_load_lds(
      (const __attribute__((address_space(1))) unsigned*)g,
      (__attribute__((address_space(3))) unsigned*)l, 16, 0, 0);
}

// ---- prep kernels -----------------------------------------------------------

__global__ __launch_bounds__(256) void k_convert_w(const float* __restrict__ W,
                                                   unsigned short* __restrict__ Wh,
                                                   unsigned short* __restrict__ Wx) {
  int idx = blockIdx.x * 256 + threadIdx.x;          // 4096*2048/4 = 2097152 total
  f32x4 v = ((const f32x4*)W)[idx];
  u16x4 o;
#pragma unroll
  for (int e = 0; e < 4; ++e) o[e] = f2bf(v[e]);
  int n   = idx >> 9;                                // 512 float4 per 2048-col row
  int col = (idx & 511) * 4;
  if (col < 1024) *(u16x4*)(Wh + (size_t)n * 1024 + col)          = o;
  else            *(u16x4*)(Wx + (size_t)n * 1024 + (col - 1024)) = o;
}

// xb region later becomes the h ring buffer, written with sc0sc1 (write-
// through). To guarantee NO dirty L2 line of this region can ever be written
// back late and clobber ring data, xb itself is also stored write-through.
__global__ __launch_bounds__(256) void k_convert_x(const float* __restrict__ x,
                                                   unsigned short* __restrict__ xb) {
  int idx = blockIdx.x * 256 + threadIdx.x;          // 16777216/4 = 4194304 total
  f32x4 v = ((const f32x4*)x)[idx];
  u16x4 o;
#pragma unroll
  for (int e = 0; e < 4; ++e) o[e] = f2bf(v[e]);
  unsigned long long val;
  __builtin_memcpy(&val, &o, 8);
  unsigned short* p = xb + (size_t)idx * 4;
  asm volatile("global_store_dwordx2 %0, %1, off sc0 sc1"
               :: "v"(p), "v"(val) : "memory");
}

__global__ __launch_bounds__(256) void k_zero_wt(unsigned* __restrict__ p, int n) {
  int i = blockIdx.x * 256 + threadIdx.x;
  unsigned z = 0u;
  if (i < n)
    asm volatile("global_store_dword %0, %1, off sc0 sc1"
                 :: "v"(p + i), "v"(z) : "memory");
}

// ---- x-projection GEMM: Gx[m][n] = sum_d x[m][d] * Wx[n][d] (fp16 out) ------
// m97 structure: 128x128 tile, BK=64, global_load_lds width-16 staging.

__global__ __launch_bounds__(256) void k_xgemm(const unsigned short* __restrict__ A,
                                               const unsigned short* __restrict__ Bw,
                                               __half* __restrict__ C) {
  __shared__ unsigned short sA[128 * 64];
  __shared__ unsigned short sB[128 * 64];
  const int m0 = blockIdx.x * 128;
  const int n0 = blockIdx.y * 128;
  const int tid = threadIdx.x;
  const int lane = tid & 63;
  const int w = tid >> 6;
  const int wm = w >> 1, wn = w & 1;
  f32x4 acc[4][4] = {};
  for (int k0 = 0; k0 < 1024; k0 += 64) {
#pragma unroll
    for (int it = 0; it < 4; ++it) {
      int chunk = it * 256 + w * 64 + lane;
      int row = chunk >> 3, kc = chunk & 7;
      gload_lds16(A + (size_t)(m0 + row) * 1024 + k0 + kc * 8,
                  (char*)sA + (size_t)(it * 256 + w * 64) * 16);
      gload_lds16(Bw + (size_t)(n0 + row) * 1024 + k0 + kc * 8,
                  (char*)sB + (size_t)(it * 256 + w * 64) * 16);
    }
    asm volatile("s_waitcnt vmcnt(0)" ::: "memory");
    __syncthreads();
#pragma unroll
    for (int ks = 0; ks < 2; ++ks) {
      short8 af[4], bfr[4];
#pragma unroll
      for (int i = 0; i < 4; ++i) {
        int arow = wm * 64 + i * 16 + (lane & 15);
        af[i] = *(const short8*)(sA + arow * 64 + ks * 32 + (lane >> 4) * 8);
      }
#pragma unroll
      for (int j = 0; j < 4; ++j) {
        int brow = wn * 64 + j * 16 + (lane & 15);
        bfr[j] = *(const short8*)(sB + brow * 64 + ks * 32 + (lane >> 4) * 8);
      }
#pragma unroll
      for (int i = 0; i < 4; ++i)
#pragma unroll
        for (int j = 0; j < 4; ++j)
          acc[i][j] = __builtin_amdgcn_mfma_f32_16x16x32_bf16(af[i], bfr[j], acc[i][j], 0, 0, 0);
    }
    __syncthreads();
  }
#pragma unroll
  for (int i = 0; i < 4; ++i)
#pragma unroll
    for (int j = 0; j < 4; ++j)
#pragma unroll
      for (int q = 0; q < 4; ++q) {
        int row = m0 + wm * 64 + i * 16 + (lane >> 4) * 4 + q;
        int col = n0 + wn * 64 + j * 16 + (lane & 15);
        C[(size_t)row * NG + col] = __float2half(acc[i][j][q]);
      }
}

// ---- persistent recurrent kernel -------------------------------------------
// 128 WGs x 256 threads (1 WG/CU -> co-resident). WG wg owns hidden j0..j0+7
// across all 4 gates (32 gate columns). Wh slice in XOR-swizzled LDS; h_t
// MFMA A-fragments are loaded DIRECTLY from the ring (no LDS round-trip):
// lane l reads 16B at row (l&15), k-offset (l>>4)*16 - fully-coalesced
// global_load_dwordx4 (16 rows x 64B whole lines per instruction). Consumed
// in 4 groups of 8 with counted vmcnt + sched_barrier(0) (rule #18); the
// group's Wh B-fragments are ds_read-issued before each vmcnt so LDS latency
// hides under the load wait.
//
// Cross-step h exchange via a 512-SLOT RING (slot t = h_t, 64 KB each):
// producers store slot t+1 with sc0 sc1 (write-through to the coherence
// point; vmcnt(0) ack precedes the flag). Consumers read slots with normal
// cached loads - safe without fences because each slot line is written
// exactly once before its first read in this launch (kernel-start acquire
// fence drops stale clean copies from k_xgemm / prior replays). Flags are
// polled with sc0sc1 (never cached).

__global__ __launch_bounds__(256, 1) void k_lstm(const unsigned short* __restrict__ Whg,
                                                 const __half* __restrict__ Gx,
                                                 const float* __restrict__ bias,
                                                 unsigned short* __restrict__ ring,
                                                 float* __restrict__ out,
                                                 unsigned* __restrict__ flags) {
  extern __shared__ char lds[];
  char* w_base = lds;                               // 65536 B, swizzled [32][1024] bf16
  float* gates_s = (float*)(lds + 65536);           // [32][33] fp32
  float* bias_s  = (float*)(lds + 65536 + 4224);    // [32]
  unsigned short* hlds = (unsigned short*)(lds + 65536 + 4224 + 128); // [256]

  const int tid = threadIdx.x;
  const int lane = tid & 63;
  const int w = tid >> 6;
  const int wg = blockIdx.x;
  const int j0 = wg * 8;

  // acquire: drop stale clean cached lines of the ring region (k_xgemm reads
  // of x / prior replay) before any cached ring read in this launch.
  __builtin_amdgcn_fence(__ATOMIC_ACQUIRE, "agent");

  // Stage Wh slice once: local col c (0..31) -> global gate row (c>>3)*1024 + j0 + (c&7)
  for (int i = tid; i < 4096; i += 256) {           // 32 rows * 128 16B-chunks
    int c = i >> 7, kc = i & 127;
    int n = (c >> 3) * 1024 + j0 + (c & 7);
    u32x4 v = *(const u32x4*)(Whg + (size_t)n * 1024 + kc * 8);
    *(u32x4*)(w_base + c * 2048 + ((kc * 16) ^ ((c & 7) << 4))) = v;
  }
  if (tid < 32) bias_s[tid] = bias[(tid >> 3) * 1024 + j0 + (tid & 7)];
  __syncthreads();

  const int mt = w >> 1, nt = w & 1;
  const int brow = nt * 16 + (lane & 15);
  const char* bBase = w_base + brow * 2048;
  const int kslot = (lane >> 4) * 16;
  const int bswz = (brow & 7) << 4;
  const int b_ = tid >> 3, jj = tid & 7;
  const float rb0 = bias_s[jj], rb1 = bias_s[8 + jj];
  const float rb2 = bias_s[16 + jj], rb3 = bias_s[24 + jj];
  // per-lane A offset within a ring slot: row (lane&15) of wave's m-tile
  const size_t a_off = (size_t)(mt * 16 + (lane & 15)) * 2048 + (size_t)(lane >> 4) * 16;
  float c_reg = 0.f;                                // cell state (thread-private)

  // poll pointers (wave 0): lane covers flags[2*lane] and flags[2*lane+1], 64B-spread
  const unsigned* fp0 = flags + (size_t)(2 * tid) * 16;
  const unsigned* fp1 = flags + (size_t)(2 * tid + 1) * 16;

  for (int t = 0; t < 512; ++t) {
    const char* aG = (const char*)ring + (size_t)t * 65536 + a_off;  // slot t
    unsigned short* hout = ring + (size_t)(t + 1) * 32768;           // slot t+1

    // ---- issue VMEM in fixed order: 4 Gx loads, then 32 A-fragment loads ----
    const char* gxp = (const char*)(Gx + ((size_t)(b_ * L_SZ + t)) * NG + j0 + jj);
    unsigned gxa, gxb, gxc, gxd;
    asm volatile("global_load_ushort %0, %1, off" : "=v"(gxa) : "v"(gxp)        : "memory");
    asm volatile("global_load_ushort %0, %1, off" : "=v"(gxb) : "v"(gxp + 2048) : "memory");
    asm volatile("global_load_ushort %0, %1, off" : "=v"(gxc) : "v"(gxp + 4096) : "memory");
    asm volatile("global_load_ushort %0, %1, off" : "=v"(gxd) : "v"(gxp + 6144) : "memory");

    u32x4 areg[32];
    if (t) {
#pragma unroll
      for (int ks = 0; ks < 32; ++ks)
        asm volatile("global_load_dwordx4 %0, %1, off offset:%2"
                     : "=v"(areg[ks]) : "v"(aG), "n"(ks * 64) : "memory");
    } else {
#pragma unroll
      for (int ks = 0; ks < 32; ++ks) areg[ks] = (u32x4){0u, 0u, 0u, 0u};
    }

    // ---- gates(32x32) = h_t @ Wh_slice^T, A from regs, B from LDS ----
    f32x4 acc0 = {0.f, 0.f, 0.f, 0.f}, acc1 = {0.f, 0.f, 0.f, 0.f};
#pragma unroll
    for (int g = 0; g < 4; ++g) {
      short8 bfr[8];
#pragma unroll
      for (int k = 0; k < 8; ++k) {                 // B ds_reads issued pre-vmcnt
        int ks = g * 8 + k;
        bfr[k] = *(const short8*)(bBase + ((ks * 64 + kslot) ^ bswz));
      }
      if (t) {
        if (g == 0)      asm volatile("s_waitcnt vmcnt(24)" ::: "memory");
        else if (g == 1) asm volatile("s_waitcnt vmcnt(16)" ::: "memory");
        else if (g == 2) asm volatile("s_waitcnt vmcnt(8)"  ::: "memory");
        else             asm volatile("s_waitcnt vmcnt(0)"  ::: "memory");
        __builtin_amdgcn_sched_barrier(0);
      }
#pragma unroll
      for (int k = 0; k < 8; k += 2) {
        int ks = g * 8 + k;
        short8 a0, a1;
        __builtin_memcpy(&a0, &areg[ks], 16);
        __builtin_memcpy(&a1, &areg[ks + 1], 16);
        acc0 = __builtin_amdgcn_mfma_f32_16x16x32_bf16(a0, bfr[k],     acc0, 0, 0, 0);
        acc1 = __builtin_amdgcn_mfma_f32_16x16x32_bf16(a1, bfr[k + 1], acc1, 0, 0, 0);
      }
    }
    f32x4 acc = acc0 + acc1;
#pragma unroll
    for (int q = 0; q < 4; ++q)                     // disjoint per-wave quadrant
      gates_s[(mt * 16 + (lane >> 4) * 4 + q) * 33 + nt * 16 + (lane & 15)] = acc[q];
    __syncthreads();

    // ---- elementwise gating: thread -> (batch b_, hidden j0+jj) ----
    asm volatile("s_waitcnt vmcnt(0)" ::: "memory");    // Gx ready (free if drained)
    float hn;
    {
      float sf = gates_s[b_ * 33 + jj]      + __half2float(__ushort_as_half((unsigned short)gxa)) + rb0;
      float si = gates_s[b_ * 33 + 8 + jj]  + __half2float(__ushort_as_half((unsigned short)gxb)) + rb1;
      float so = gates_s[b_ * 33 + 16 + jj] + __half2float(__ushort_as_half((unsigned short)gxc)) + rb2;
      float sc = gates_s[b_ * 33 + 24 + jj] + __half2float(__ushort_as_half((unsigned short)gxd)) + rb3;
      float gf = 1.f / (1.f + expf(-sf));
      float gi = 1.f / (1.f + expf(-si));
      float go = 1.f / (1.f + expf(-so));
      float cn = gf * c_reg + gi * tanhf(sc);
      hn = go * tanhf(cn);
      c_reg = cn;
      hlds[tid] = f2bf(hn);                         // hlds[b_*8+jj] == hlds[tid]
    }
    float* outp = out + ((size_t)b_ * L_SZ + t) * H_SZ + j0 + jj;

    if (t < 511) {
      __syncthreads();                                  // hlds complete
      if (tid < 32) {                                   // packed h store: 32 x 16B
        u32x4 v = *(u32x4*)(hlds + tid * 8);
        unsigned short* hp = hout + (size_t)tid * H_SZ + j0;
        asm volatile("global_store_dwordx4 %0, %1, off sc0 sc1"
                     :: "v"(hp), "v"(v) : "memory");
      }
      // all h stores are wave 0's -> wave 0's own drain suffices for the flag
      asm volatile("s_waitcnt vmcnt(0)" ::: "memory");  // h stores at coherence point
      if (tid == 0) {                                   // parallel-store flag barrier
        unsigned fv = (unsigned)(t + 1);
        const unsigned* myf = flags + (size_t)wg * 16;
        asm volatile("global_store_dword %0, %1, off sc0 sc1"
                     :: "v"(myf), "v"(fv) : "memory");
      }
      *outp = hn;                                       // cached store, off critical path
      if (tid < 64) {                                   // wave 0 polls all 128 flags
        unsigned fa, fb;
        do {
          asm volatile("global_load_dword %0, %2, off sc0 sc1\n\t"
                       "global_load_dword %1, %3, off sc0 sc1\n\t"
                       "s_waitcnt vmcnt(0)"
                       : "=v"(fa), "=v"(fb) : "v"(fp0), "v"(fp1) : "memory");
        } while (!__all(fa > (unsigned)t && fb > (unsigned)t));
      }
      __syncthreads();                                  // all producers done
    } else {
      *outp = hn;
    }
  }
}

// ---- host launcher ----------------------------------------------------------

extern "C" void kernel_launch(void* const* d_in, const int* in_sizes, int n_in,
                              void* d_out, int out_size, void* d_ws, size_t ws_size,
                              hipStream_t stream) {
  const float* x = (const float*)d_in[0];
  const float* W = (const float*)d_in[1];
  const float* b = (const float*)d_in[2];
  char* ws = (char*)d_ws;
  __half* Gx           = (__half*)(ws + GX_OFF);
  unsigned short* xb   = (unsigned short*)(ws + XB_OFF);   // becomes h ring
  unsigned short* Wh   = (unsigned short*)(ws + WH_OFF);
  unsigned short* Wx   = (unsigned short*)(ws + WX_OFF);
  unsigned* flags      = (unsigned*)(ws + FLG_OFF);
  float* out = (float*)d_out;

  // prep: bf16 conversions + zero flags (re-zeroed every call -> deterministic)
  k_convert_w<<<8192, 256, 0, stream>>>(W, Wh, Wx);
  k_convert_x<<<16384, 256, 0, stream>>>(x, xb);
  k_zero_wt<<<8, 256, 0, stream>>>(flags, 8192 / 4);

  // input projection for all timesteps
  k_xgemm<<<dim3(128, 32), 256, 0, stream>>>(xb, Wx, Gx);

  // persistent recurrence (70400 B dynamic LDS > 64KB default -> raise cap)
  hipFuncSetAttribute((const void*)k_lstm,
                      hipFuncAttributeMaxDynamicSharedMemorySize, 70400);
  k_lstm<<<128, 256, 70400, stream>>>(Wh, Gx, b, xb, out, flags);
}